// Round 2
// baseline (1253.010 us; speedup 1.0000x reference)
//
#include <hip/hip_runtime.h>
#include <hip/hip_bf16.h>
#include <math.h>

// Problem constants
#define L_ 1024
#define B_ 4
#define D_ 1024
#define E_ 8
#define K_ 2
#define H_ 4096
#define T_ (L_*B_)        // 4096 tokens
#define P_ (T_*K_)        // 8192 token-expert pairs
#define PPAD (P_+128)     // padded rows so partial GEMM tiles can over-read safely

typedef unsigned short u16;
typedef __attribute__((ext_vector_type(4))) float f32x4;
typedef __attribute__((ext_vector_type(8))) short s16x8;

__device__ __forceinline__ u16 f2bf(float f) {
  uint32_t u = __float_as_uint(f);
  uint32_t r = (u + 0x7FFFu + ((u >> 16) & 1u)) >> 16;  // RNE
  return (u16)r;
}
__device__ __forceinline__ float gelu_tanh(float v) {
  float c = v + 0.044715f * v * v * v;
  return 0.5f * v * (1.0f + tanhf(0.7978845608028654f * c));
}

// ---------------------------------------------------------------------------
// fp32 [E][R][C] -> bf16 [E][C][R]  (transpose + convert, 64x64 LDS tiles)
// ---------------------------------------------------------------------------
template<int R, int C>
__global__ void convtrans(const float* __restrict__ in, u16* __restrict__ out) {
  __shared__ float tile[64][65];
  int e = blockIdx.z;
  int r0 = blockIdx.y * 64, c0 = blockIdx.x * 64;
  const float* src = in + (size_t)e * R * C;
  u16* dst = out + (size_t)e * R * C;
  int t = threadIdx.x;
  int tr = t >> 4, tc = (t & 15) * 4;
#pragma unroll
  for (int p = 0; p < 4; ++p) {
    int r = tr + p * 16;
    float4 v = *(const float4*)(src + (size_t)(r0 + r) * C + c0 + tc);
    tile[r][tc] = v.x; tile[r][tc+1] = v.y; tile[r][tc+2] = v.z; tile[r][tc+3] = v.w;
  }
  __syncthreads();
#pragma unroll
  for (int p = 0; p < 4; ++p) {
    int c = tr + p * 16;
    ushort4 o;
    o.x = f2bf(tile[tc+0][c]); o.y = f2bf(tile[tc+1][c]);
    o.z = f2bf(tile[tc+2][c]); o.w = f2bf(tile[tc+3][c]);
    *(ushort4*)(dst + (size_t)(c0 + c) * R + r0 + tc) = o;
  }
}

// ---------------------------------------------------------------------------
// Gating: one wave per token. fp32 logits (must match reference top-k).
// ---------------------------------------------------------------------------
__global__ void gating(const float* __restrict__ x, const float* __restrict__ task_param,
                       const float* __restrict__ gw_img, const float* __restrict__ gb_img,
                       const float* __restrict__ gw_txt, const float* __restrict__ gb_txt,
                       const float* __restrict__ tgw, const float* __restrict__ tgb,
                       const float* __restrict__ alpha_p, const int* __restrict__ is_text_p,
                       float4* __restrict__ sel_w, float* __restrict__ prob_part,
                       int* __restrict__ count_part) {
  __shared__ float wprob[4][8];
  __shared__ int wcnt[4][8];
  int wid = threadIdx.x >> 6, lane = threadIdx.x & 63;
  int t = blockIdx.x * 4 + wid;
  int b = t & (B_ - 1);
  int it = is_text_p[0];
  const float* gw = it ? gw_txt : gw_img;
  const float* gb = it ? gb_txt : gb_img;
  float alpha = alpha_p[0];
  const float* xr = x + (size_t)t * D_;
  const float* tp = task_param + (size_t)b * D_;
  float acc[8] = {0,0,0,0,0,0,0,0};
  float tac[8] = {0,0,0,0,0,0,0,0};
  for (int i = 0; i < D_/64; ++i) {
    int d = i * 64 + lane;
    float xv = xr[d], tv = tp[d];
#pragma unroll
    for (int e = 0; e < 8; ++e) {
      acc[e] += xv * gw[d*8 + e];
      tac[e] += tv * tgw[d*8 + e];
    }
  }
#pragma unroll
  for (int e = 0; e < 8; ++e) {
#pragma unroll
    for (int off = 32; off > 0; off >>= 1) {
      acc[e] += __shfl_xor(acc[e], off);
      tac[e] += __shfl_xor(tac[e], off);
    }
  }
  float lg[8];
#pragma unroll
  for (int e = 0; e < 8; ++e)
    lg[e] = (1.0f - alpha) * (acc[e] + gb[e]) + alpha * (tac[e] + tgb[e]);
  // full softmax (for l_aux)
  float m = lg[0];
#pragma unroll
  for (int e = 1; e < 8; ++e) m = fmaxf(m, lg[e]);
  float pr[8], ps = 0.f;
#pragma unroll
  for (int e = 0; e < 8; ++e) { pr[e] = expf(lg[e] - m); ps += pr[e]; }
  float inv = 1.0f / ps;
  // top-2 (ties -> lowest index, matching lax.top_k)
  int i0 = 0; float v0 = lg[0];
#pragma unroll
  for (int e = 1; e < 8; ++e) if (lg[e] > v0) { v0 = lg[e]; i0 = e; }
  int i1 = -1; float v1 = -1e30f;
#pragma unroll
  for (int e = 0; e < 8; ++e) if (e != i0 && lg[e] > v1) { v1 = lg[e]; i1 = e; }
  float ex = expf(v1 - v0);
  float w0 = 1.0f / (1.0f + ex), w1 = ex / (1.0f + ex);
  if (lane == 0) {
    sel_w[t] = make_float4(__int_as_float(i0), __int_as_float(i1), w0, w1);
#pragma unroll
    for (int e = 0; e < 8; ++e) {
      wprob[wid][e] = pr[e] * inv;
      wcnt[wid][e] = (i0 == e) + (i1 == e);
    }
  }
  __syncthreads();
  if (threadIdx.x < 8) {
    int e = threadIdx.x;
    prob_part[blockIdx.x * 8 + e] = wprob[0][e] + wprob[1][e] + wprob[2][e] + wprob[3][e];
    count_part[blockIdx.x * 8 + e] = wcnt[0][e] + wcnt[1][e] + wcnt[2][e] + wcnt[3][e];
  }
}

// ---------------------------------------------------------------------------
// Finalize: deterministic reduce of partials -> counts/offsets/cursors + l_aux
// ---------------------------------------------------------------------------
__global__ void finalize(const float* __restrict__ prob_part, const int* __restrict__ count_part,
                         int* __restrict__ counts, int* __restrict__ offs,
                         int* __restrict__ cursors, float* __restrict__ laux_out) {
  __shared__ float ps_[256];
  __shared__ int cs_[256];
  int t = threadIdx.x;
  int e = t & 7, s = t >> 3;  // 32 strided chunks per expert
  float p = 0.f; int c = 0;
  for (int b = s; b < 1024; b += 32) { p += prob_part[b*8 + e]; c += count_part[b*8 + e]; }
  ps_[t] = p; cs_[t] = c;
  __syncthreads();
  for (int st = 16; st > 0; st >>= 1) {
    if (s < st) { ps_[t] += ps_[t + st*8]; cs_[t] += cs_[t + st*8]; }
    __syncthreads();
  }
  if (t == 0) {
    int off = 0; float laux = 0.f;
    for (int ee = 0; ee < 8; ++ee) {
      int cnt = cs_[ee];
      counts[ee] = cnt; offs[ee] = off; cursors[ee] = off; off += cnt;
      laux += (ps_[ee] * (1.0f/4096.0f)) * ((float)cnt * (1.0f/4096.0f));
    }
    *laux_out = laux;
  }
}

// ---------------------------------------------------------------------------
// Scatter + gather: assign bucket slots, record token->pair map, gather bf16 rows
// ---------------------------------------------------------------------------
__global__ void scatter_gather(const float* __restrict__ x, const float4* __restrict__ sel_w,
                               int* __restrict__ cursors, float* __restrict__ pair_w,
                               int* __restrict__ pair_idx, u16* __restrict__ Xg) {
  int wid = threadIdx.x >> 6, lane = threadIdx.x & 63;
  int t = blockIdx.x * 4 + wid;
  float4 sw = sel_w[t];
  int s0 = __float_as_int(sw.x), s1 = __float_as_int(sw.y);
  int p0 = 0, p1 = 0;
  if (lane == 0) {
    p0 = atomicAdd(&cursors[s0], 1);
    p1 = atomicAdd(&cursors[s1], 1);
  }
  p0 = __shfl(p0, 0); p1 = __shfl(p1, 0);
  if (lane == 0) {
    pair_w[p0] = sw.z; pair_w[p1] = sw.w;
    pair_idx[t*2] = p0; pair_idx[t*2+1] = p1;
  }
  const float* xr = x + (size_t)t * D_;
  u16* d0 = Xg + (size_t)p0 * D_;
  u16* d1 = Xg + (size_t)p1 * D_;
#pragma unroll
  for (int i = 0; i < 4; ++i) {
    int c = i * 256 + lane * 4;
    float4 v = *(const float4*)(xr + c);
    ushort4 o;
    o.x = f2bf(v.x); o.y = f2bf(v.y); o.z = f2bf(v.z); o.w = f2bf(v.w);
    *(ushort4*)(d0 + c) = o;
    *(ushort4*)(d1 + c) = o;
  }
}

// ---------------------------------------------------------------------------
// Grouped GEMM, pipelined (bf16 MFMA 16x16x32, 128x128 tile, BK=32).
//  - LDS layout is fragment-contiguous: tile stored as [g=row/16][lane][8 elems]
//    so MFMA fragment reads are ds_read_b128 at (g*64+lane)*16B -> linear,
//    ZERO bank conflicts. global_load_lds keeps a linear LDS dest (wave-uniform
//    base + lane*16B); the per-lane GLOBAL address carries the permutation.
//  - 3 LDS buffers, 2-deep prefetch, counted s_waitcnt vmcnt(4) (never 0
//    mid-loop), raw s_barrier (1/iter), lgkmcnt(0)+sched_barrier before MFMA,
//    setprio(1) around the MFMA cluster.
//    Race check: stage at iter t targets buf[(t+2)%3] == buf[(t-1)%3]; the
//    barrier at iter t's top guarantees every wave finished iter t-1's
//    ds_reads (drained by its lgkmcnt(0) before MFMA). vmcnt(4) at iter top
//    leaves tile t+1's 4 loads in flight; barrier after each wave's own
//    vmcnt makes tile t globally visible in LDS.
// EPI==0: Hout[row][n] = bf16(gelu(acc))   EPI==1: Cout[row][n] = acc * pair_w[row]
// ---------------------------------------------------------------------------
template<int EPI, int KDIM, int NDIM>
__global__ __launch_bounds__(256)
void gemm_ffn(const u16* __restrict__ A, const u16* __restrict__ Bmat,
              const int* __restrict__ counts, const int* __restrict__ offs,
              const float* __restrict__ pair_w,
              u16* __restrict__ Hout, float* __restrict__ Cout) {
  int e = blockIdx.z;
  int ne = counts[e];
  int bx = blockIdx.x;
  if (bx * 128 >= ne) return;
  int off = offs[e];
  int n0 = blockIdx.y * 128;
  __shared__ u16 As[3][4096];   // [g][lane][8] per buffer = 8KB
  __shared__ u16 Bs[3][4096];
  int t = threadIdx.x;
  int lane = t & 63, wid = t >> 6;
  int wm = (wid >> 1) * 64, wn = (wid & 1) * 64;
  const u16* Ag = A + (size_t)(off + bx * 128) * KDIM;
  const u16* Bg = Bmat + (size_t)e * NDIM * KDIM + (size_t)n0 * KDIM;
  f32x4 acc[4][4] = {};

  // staging: wave `wid` covers g-groups {2*wid, 2*wid+1} of A and B.
  // global element for LDS slot (g, lane, 0..7): row = g*16+(lane&15),
  // k = k0 + (lane>>4)*8  (identical mapping to the MFMA fragment read).
  int srow0 = (wid * 2) * 16 + (lane & 15);
  int skk   = (lane >> 4) << 3;
  auto stage = [&](int b, int k0) {
#pragma unroll
    for (int i = 0; i < 2; ++i) {
      int g = wid * 2 + i;
      const u16* ga = Ag + (size_t)(srow0 + i * 16) * KDIM + k0 + skk;
      const u16* gb = Bg + (size_t)(srow0 + i * 16) * KDIM + k0 + skk;
      __builtin_amdgcn_global_load_lds(
          (const __attribute__((address_space(1))) void*)ga,
          (__attribute__((address_space(3))) void*)(&As[b][(g * 64 + lane) * 8]), 16, 0, 0);
      __builtin_amdgcn_global_load_lds(
          (const __attribute__((address_space(1))) void*)gb,
          (__attribute__((address_space(3))) void*)(&Bs[b][(g * 64 + lane) * 8]), 16, 0, 0);
    }
  };

  constexpr int NT = KDIM / 32;
  stage(0, 0);
  stage(1, 32);
  int gm = wm >> 4, gn = wn >> 4;
  int sb = 2, cb = 0;
  for (int tt = 0; tt < NT; ++tt) {
    if (tt + 1 < NT) asm volatile("s_waitcnt vmcnt(4)" ::: "memory");
    else             asm volatile("s_waitcnt vmcnt(0)" ::: "memory");
    __builtin_amdgcn_s_barrier();
    asm volatile("" ::: "memory");
    if (tt + 2 < NT) {
      stage(sb, (tt + 2) * 32);
      sb = (sb == 2) ? 0 : sb + 1;
    }
    s16x8 af[4], bfv[4];
#pragma unroll
    for (int r = 0; r < 4; ++r) af[r] = *(const s16x8*)&As[cb][((gm + r) * 64 + lane) * 8];
#pragma unroll
    for (int f = 0; f < 4; ++f) bfv[f] = *(const s16x8*)&Bs[cb][((gn + f) * 64 + lane) * 8];
    cb = (cb == 2) ? 0 : cb + 1;
    asm volatile("s_waitcnt lgkmcnt(0)" ::: "memory");
    __builtin_amdgcn_sched_barrier(0);
    __builtin_amdgcn_s_setprio(1);
#pragma unroll
    for (int r = 0; r < 4; ++r)
#pragma unroll
      for (int f = 0; f < 4; ++f)
        acc[r][f] = __builtin_amdgcn_mfma_f32_16x16x32_bf16(af[r], bfv[f], acc[r][f], 0, 0, 0);
    __builtin_amdgcn_s_setprio(0);
  }

  int lr = lane & 15;
  int lg4 = (lane >> 4) * 4;
#pragma unroll
  for (int r = 0; r < 4; ++r) {
#pragma unroll
    for (int j = 0; j < 4; ++j) {
      int mloc = bx * 128 + wm + r * 16 + lg4 + j;
      if (mloc >= ne) continue;
      size_t grow = (size_t)(off + mloc);
      if (EPI == 0) {
#pragma unroll
        for (int f = 0; f < 4; ++f) {
          float v = acc[r][f][j];
          Hout[grow * NDIM + n0 + wn + f * 16 + lr] = f2bf(gelu_tanh(v));
        }
      } else {
        float w = pair_w[grow];
#pragma unroll
        for (int f = 0; f < 4; ++f) {
          Cout[grow * NDIM + n0 + wn + f * 16 + lr] = acc[r][f][j] * w;
        }
      }
    }
  }
}

// ---------------------------------------------------------------------------
// Combine: out[token] = pair_out[p0] + pair_out[p1]
// ---------------------------------------------------------------------------
__global__ void combine(const float* __restrict__ pair_out, const int* __restrict__ pair_idx,
                        float* __restrict__ out) {
  int t = blockIdx.x;
  int p0 = pair_idx[t*2], p1 = pair_idx[t*2+1];
  int c = threadIdx.x * 4;
  float4 a = *(const float4*)(pair_out + (size_t)p0 * D_ + c);
  float4 b = *(const float4*)(pair_out + (size_t)p1 * D_ + c);
  float4 o; o.x = a.x + b.x; o.y = a.y + b.y; o.z = a.z + b.z; o.w = a.w + b.w;
  *(float4*)(out + (size_t)t * D_ + c) = o;
}

// ---------------------------------------------------------------------------
// Workspace layout (bytes) — requires ~210 MiB of d_ws.
// ---------------------------------------------------------------------------
extern "C" void kernel_launch(void* const* d_in, const int* in_sizes, int n_in,
                              void* d_out, int out_size, void* d_ws, size_t ws_size,
                              hipStream_t stream) {
  const float* inputs      = (const float*)d_in[0];
  const float* task_param  = (const float*)d_in[1];
  const float* gate_img_w  = (const float*)d_in[2];
  const float* gate_img_b  = (const float*)d_in[3];
  const float* gate_txt_w  = (const float*)d_in[4];
  const float* gate_txt_b  = (const float*)d_in[5];
  const float* task_gate_w = (const float*)d_in[6];
  const float* task_gate_b = (const float*)d_in[7];
  const float* alpha       = (const float*)d_in[8];
  const float* w1          = (const float*)d_in[9];
  const float* w2          = (const float*)d_in[10];
  const int*   is_text     = (const int*)d_in[11];
  float* out = (float*)d_out;

  char* ws = (char*)d_ws;
  u16* w1b = (u16*)(ws + 0);
  u16* w2b = (u16*)(ws + 67108864);
  u16* Xg  = (u16*)(ws + 134217728);
  u16* Hb  = (u16*)(ws + 151257088);
  float4* sel_w   = (float4*)(ws + 219414528);
  float* pair_w   = (float*)(ws + 219480064);
  int* pair_idx   = (int*)(ws + 219513344);
  float* prob_part= (float*)(ws + 219546112);
  int* count_part = (int*)(ws + 219578880);
  int* counters   = (int*)(ws + 219611648);
  float* pair_out = (float*)(ws + 0);  // aliases w1b (dead after GEMM1)

  int* counts  = counters;
  int* offs    = counters + 8;
  int* cursors = counters + 16;

  convtrans<D_, H_><<<dim3(H_/64, D_/64, E_), 256, 0, stream>>>(w1, w1b);
  convtrans<H_, D_><<<dim3(D_/64, H_/64, E_), 256, 0, stream>>>(w2, w2b);
  gating<<<dim3(T_/4), 256, 0, stream>>>(inputs, task_param, gate_img_w, gate_img_b,
      gate_txt_w, gate_txt_b, task_gate_w, task_gate_b, alpha, is_text,
      sel_w, prob_part, count_part);
  finalize<<<dim3(1), 256, 0, stream>>>(prob_part, count_part, counts, offs, cursors,
      out + (size_t)T_ * D_);
  scatter_gather<<<dim3(T_/4), 256, 0, stream>>>(inputs, sel_w, cursors, pair_w, pair_idx, Xg);
  gemm_ffn<0, D_, H_><<<dim3(32, H_/128, E_), 256, 0, stream>>>(
      Xg, w1b, counts, offs, pair_w, Hb, (float*)nullptr);
  gemm_ffn<1, H_, D_><<<dim3(32, D_/128, E_), 256, 0, stream>>>(
      Hb, w2b, counts, offs, pair_w, (u16*)nullptr, pair_out);
  combine<<<dim3(T_), 256, 0, stream>>>(pair_out, pair_idx, out);
}

// Round 3
// 958.125 us; speedup vs baseline: 1.3078x; 1.3078x over previous
//
#include <hip/hip_runtime.h>
#include <hip/hip_bf16.h>
#include <math.h>

// Problem constants
#define L_ 1024
#define B_ 4
#define D_ 1024
#define E_ 8
#define K_ 2
#define H_ 4096
#define T_ (L_*B_)        // 4096 tokens
#define P_ (T_*K_)        // 8192 token-expert pairs
#define PPAD (P_+128)     // padded rows so partial GEMM tiles can over-read safely

typedef unsigned short u16;
typedef __attribute__((ext_vector_type(4))) float f32x4;
typedef __attribute__((ext_vector_type(8))) short s16x8;

__device__ __forceinline__ u16 f2bf(float f) {
  uint32_t u = __float_as_uint(f);
  uint32_t r = (u + 0x7FFFu + ((u >> 16) & 1u)) >> 16;  // RNE
  return (u16)r;
}
// gelu tanh-approx in sigmoid form: 0.5v(1+tanh(c(v+0.044715v^3))) = v*sigma(2c*u)
__device__ __forceinline__ float gelu_fast(float v) {
  float u = v * (1.0f + 0.044715f * v * v);
  float t = __expf(-1.5957691216057308f * u);   // 2*0.7978845608...
  return v / (1.0f + t);
}

// ---------------------------------------------------------------------------
// fp32 [E][R][C] -> bf16 [E][C][R]  (transpose + convert, 64x64 LDS tiles)
// ---------------------------------------------------------------------------
template<int R, int C>
__global__ void convtrans(const float* __restrict__ in, u16* __restrict__ out) {
  __shared__ float tile[64][65];
  int e = blockIdx.z;
  int r0 = blockIdx.y * 64, c0 = blockIdx.x * 64;
  const float* src = in + (size_t)e * R * C;
  u16* dst = out + (size_t)e * R * C;
  int t = threadIdx.x;
  int tr = t >> 4, tc = (t & 15) * 4;
#pragma unroll
  for (int p = 0; p < 4; ++p) {
    int r = tr + p * 16;
    float4 v = *(const float4*)(src + (size_t)(r0 + r) * C + c0 + tc);
    tile[r][tc] = v.x; tile[r][tc+1] = v.y; tile[r][tc+2] = v.z; tile[r][tc+3] = v.w;
  }
  __syncthreads();
#pragma unroll
  for (int p = 0; p < 4; ++p) {
    int c = tr + p * 16;
    ushort4 o;
    o.x = f2bf(tile[tc+0][c]); o.y = f2bf(tile[tc+1][c]);
    o.z = f2bf(tile[tc+2][c]); o.w = f2bf(tile[tc+3][c]);
    *(ushort4*)(dst + (size_t)(c0 + c) * R + r0 + tc) = o;
  }
}

// ---------------------------------------------------------------------------
// Gating: one wave per token. fp32 logits (must match reference top-k).
// ---------------------------------------------------------------------------
__global__ void gating(const float* __restrict__ x, const float* __restrict__ task_param,
                       const float* __restrict__ gw_img, const float* __restrict__ gb_img,
                       const float* __restrict__ gw_txt, const float* __restrict__ gb_txt,
                       const float* __restrict__ tgw, const float* __restrict__ tgb,
                       const float* __restrict__ alpha_p, const int* __restrict__ is_text_p,
                       float4* __restrict__ sel_w, float* __restrict__ prob_part,
                       int* __restrict__ count_part) {
  __shared__ float wprob[4][8];
  __shared__ int wcnt[4][8];
  int wid = threadIdx.x >> 6, lane = threadIdx.x & 63;
  int t = blockIdx.x * 4 + wid;
  int b = t & (B_ - 1);
  int it = is_text_p[0];
  const float* gw = it ? gw_txt : gw_img;
  const float* gb = it ? gb_txt : gb_img;
  float alpha = alpha_p[0];
  const float* xr = x + (size_t)t * D_;
  const float* tp = task_param + (size_t)b * D_;
  float acc[8] = {0,0,0,0,0,0,0,0};
  float tac[8] = {0,0,0,0,0,0,0,0};
  for (int i = 0; i < D_/64; ++i) {
    int d = i * 64 + lane;
    float xv = xr[d], tv = tp[d];
#pragma unroll
    for (int e = 0; e < 8; ++e) {
      acc[e] += xv * gw[d*8 + e];
      tac[e] += tv * tgw[d*8 + e];
    }
  }
#pragma unroll
  for (int e = 0; e < 8; ++e) {
#pragma unroll
    for (int off = 32; off > 0; off >>= 1) {
      acc[e] += __shfl_xor(acc[e], off);
      tac[e] += __shfl_xor(tac[e], off);
    }
  }
  float lg[8];
#pragma unroll
  for (int e = 0; e < 8; ++e)
    lg[e] = (1.0f - alpha) * (acc[e] + gb[e]) + alpha * (tac[e] + tgb[e]);
  // full softmax (for l_aux)
  float m = lg[0];
#pragma unroll
  for (int e = 1; e < 8; ++e) m = fmaxf(m, lg[e]);
  float pr[8], ps = 0.f;
#pragma unroll
  for (int e = 0; e < 8; ++e) { pr[e] = expf(lg[e] - m); ps += pr[e]; }
  float inv = 1.0f / ps;
  // top-2 (ties -> lowest index, matching lax.top_k)
  int i0 = 0; float v0 = lg[0];
#pragma unroll
  for (int e = 1; e < 8; ++e) if (lg[e] > v0) { v0 = lg[e]; i0 = e; }
  int i1 = -1; float v1 = -1e30f;
#pragma unroll
  for (int e = 0; e < 8; ++e) if (e != i0 && lg[e] > v1) { v1 = lg[e]; i1 = e; }
  float ex = expf(v1 - v0);
  float w0 = 1.0f / (1.0f + ex), w1 = ex / (1.0f + ex);
  if (lane == 0) {
    sel_w[t] = make_float4(__int_as_float(i0), __int_as_float(i1), w0, w1);
#pragma unroll
    for (int e = 0; e < 8; ++e) {
      wprob[wid][e] = pr[e] * inv;
      wcnt[wid][e] = (i0 == e) + (i1 == e);
    }
  }
  __syncthreads();
  if (threadIdx.x < 8) {
    int e = threadIdx.x;
    prob_part[blockIdx.x * 8 + e] = wprob[0][e] + wprob[1][e] + wprob[2][e] + wprob[3][e];
    count_part[blockIdx.x * 8 + e] = wcnt[0][e] + wcnt[1][e] + wcnt[2][e] + wcnt[3][e];
  }
}

// ---------------------------------------------------------------------------
// Finalize: deterministic reduce of partials -> counts/offsets/cursors + l_aux
// ---------------------------------------------------------------------------
__global__ void finalize(const float* __restrict__ prob_part, const int* __restrict__ count_part,
                         int* __restrict__ counts, int* __restrict__ offs,
                         int* __restrict__ cursors, float* __restrict__ laux_out) {
  __shared__ float ps_[256];
  __shared__ int cs_[256];
  int t = threadIdx.x;
  int e = t & 7, s = t >> 3;  // 32 strided chunks per expert
  float p = 0.f; int c = 0;
  for (int b = s; b < 1024; b += 32) { p += prob_part[b*8 + e]; c += count_part[b*8 + e]; }
  ps_[t] = p; cs_[t] = c;
  __syncthreads();
  for (int st = 16; st > 0; st >>= 1) {
    if (s < st) { ps_[t] += ps_[t + st*8]; cs_[t] += cs_[t + st*8]; }
    __syncthreads();
  }
  if (t == 0) {
    int off = 0; float laux = 0.f;
    for (int ee = 0; ee < 8; ++ee) {
      int cnt = cs_[ee];
      counts[ee] = cnt; offs[ee] = off; cursors[ee] = off; off += cnt;
      laux += (ps_[ee] * (1.0f/4096.0f)) * ((float)cnt * (1.0f/4096.0f));
    }
    *laux_out = laux;
  }
}

// ---------------------------------------------------------------------------
// Scatter + gather: assign bucket slots, record token->pair map, gather bf16 rows
// ---------------------------------------------------------------------------
__global__ void scatter_gather(const float* __restrict__ x, const float4* __restrict__ sel_w,
                               int* __restrict__ cursors, float* __restrict__ pair_w,
                               int* __restrict__ pair_idx, u16* __restrict__ Xg) {
  int wid = threadIdx.x >> 6, lane = threadIdx.x & 63;
  int t = blockIdx.x * 4 + wid;
  float4 sw = sel_w[t];
  int s0 = __float_as_int(sw.x), s1 = __float_as_int(sw.y);
  int p0 = 0, p1 = 0;
  if (lane == 0) {
    p0 = atomicAdd(&cursors[s0], 1);
    p1 = atomicAdd(&cursors[s1], 1);
  }
  p0 = __shfl(p0, 0); p1 = __shfl(p1, 0);
  if (lane == 0) {
    pair_w[p0] = sw.z; pair_w[p1] = sw.w;
    pair_idx[t*2] = p0; pair_idx[t*2+1] = p1;
  }
  const float* xr = x + (size_t)t * D_;
  u16* d0 = Xg + (size_t)p0 * D_;
  u16* d1 = Xg + (size_t)p1 * D_;
#pragma unroll
  for (int i = 0; i < 4; ++i) {
    int c = i * 256 + lane * 4;
    float4 v = *(const float4*)(xr + c);
    ushort4 o;
    o.x = f2bf(v.x); o.y = f2bf(v.y); o.z = f2bf(v.z); o.w = f2bf(v.w);
    *(ushort4*)(d0 + c) = o;
    *(ushort4*)(d1 + c) = o;
  }
}

// ---------------------------------------------------------------------------
// Grouped GEMM, pipelined. bf16 MFMA 16x16x32, tile 128(feature) x 128(token),
// BK=32, 3 LDS buffers, 2-deep prefetch, counted vmcnt AFTER the MFMA cluster.
//
// LDS swizzle (both-sides involution, rule 21): logical 16B slot q of a tile
// lives at physical slot q ^ ((q>>3)&3). Staging: LDS dest is LINEAR
// (lane s -> slot s, wave-uniform base + lane*16B as global_load_lds needs);
// the global source of lane s is the element of logical slot s^((s>>3)&3).
// Within any 8-lane run the XOR term is constant -> global addresses form
// 4-lane x 64B contiguous runs (coalesced, same as R1). Fragment ds_read
// applies the same XOR -> 16-lane column-slice groups spread over all 8
// bank-groups (2-way aliasing only = free).
//
// Operand roles: A(m) = WEIGHT rows [feature][K], B(n) = TOKEN rows. Output
// acc j-index walks 4 consecutive features -> vectorized epilogue stores.
// EPI==0: Hout[tok][h] = bf16(gelu(acc))   EPI==1: Cout[tok][d] = acc*pair_w
//
// Race check (3 buf, 1 barrier/iter): stage at iter tt targets buf (tt+2)%3 =
// (tt-1)%3, whose reads happened in iter tt-1 and were drained by each wave's
// lgkmcnt(0) before that iter's end-barrier -> safe. vmcnt(4) at iter end
// drains tile tt+1 (issued at iter tt-1 -> ~1.7 iters of cover), leaving
// tile tt+2's 4 loads in flight across the barrier (never vmcnt(0) mid-loop).
// ---------------------------------------------------------------------------
template<int EPI, int KDIM, int NOUT>
__global__ __launch_bounds__(256)
void gemm_ffn(const u16* __restrict__ Tok, const u16* __restrict__ Wt,
              const int* __restrict__ counts, const int* __restrict__ offs,
              const float* __restrict__ pair_w,
              u16* __restrict__ Hout, float* __restrict__ Cout) {
  int e = blockIdx.z;
  int ne = counts[e];
  int bx = blockIdx.x;              // token tile
  if (bx * 128 >= ne) return;
  int off = offs[e];
  int f0 = blockIdx.y * 128;        // feature tile (m-dim)
  __shared__ u16 As[3][4096];       // weight tiles  (8KB each)
  __shared__ u16 Bs[3][4096];       // token tiles
  int t = threadIdx.x, lane = t & 63, wid = t >> 6;
  const u16* Wg = Wt + (size_t)e * NOUT * KDIM + (size_t)f0 * KDIM;
  const u16* Tg = Tok + (size_t)(off + bx * 128) * KDIM;

  // staging: 2 instrs per wave per matrix; lane s covers physical slot s,
  // global element = logical slot s^((s>>3)&3) -> (row, k-chunk)
  const u16* pW[2]; const u16* pT[2]; int ldd[2];
#pragma unroll
  for (int i = 0; i < 2; ++i) {
    int slot = i * 256 + wid * 64 + lane;
    int ls = slot ^ ((slot >> 3) & 3);
    int row = ls >> 2, kk = (ls & 3) << 3;
    pW[i] = Wg + (size_t)row * KDIM + kk;
    pT[i] = Tg + (size_t)row * KDIM + kk;
    ldd[i] = slot * 8;              // u16 index into tile
  }
  auto stage = [&](int b, int k0) {
#pragma unroll
    for (int i = 0; i < 2; ++i) {
      __builtin_amdgcn_global_load_lds(
          (const __attribute__((address_space(1))) void*)(pW[i] + k0),
          (__attribute__((address_space(3))) void*)(&As[b][ldd[i]]), 16, 0, 0);
      __builtin_amdgcn_global_load_lds(
          (const __attribute__((address_space(1))) void*)(pT[i] + k0),
          (__attribute__((address_space(3))) void*)(&Bs[b][ldd[i]]), 16, 0, 0);
    }
  };

  // fragment read offsets (u16 index), same involution on the address
  int mbase = (wid >> 1) * 64, nbase = (wid & 1) * 64;
  int physA[4], physB[4];
#pragma unroll
  for (int r = 0; r < 4; ++r) {
    int rowm = mbase + r * 16 + (lane & 15);
    int s1 = rowm * 4 + (lane >> 4);
    physA[r] = (s1 ^ ((s1 >> 3) & 3)) * 8;
    int rown = nbase + r * 16 + (lane & 15);
    int s2 = rown * 4 + (lane >> 4);
    physB[r] = (s2 ^ ((s2 >> 3) & 3)) * 8;
  }

  constexpr int NT = KDIM / 32;
  f32x4 acc[4][4] = {};
  stage(0, 0);
  stage(1, 32);
  asm volatile("s_waitcnt vmcnt(4)" ::: "memory");
  __builtin_amdgcn_s_barrier();
  int cb = 0, sb = 2;
  for (int tt = 0; tt < NT; ++tt) {
    if (tt + 2 < NT) { stage(sb, (tt + 2) * 32); sb = (sb == 2) ? 0 : sb + 1; }
    const u16* Ab = &As[cb][0]; const u16* Bb = &Bs[cb][0];
    s16x8 am[4], bn[4];
#pragma unroll
    for (int r = 0; r < 4; ++r) {
      am[r] = *(const s16x8*)(Ab + physA[r]);
      bn[r] = *(const s16x8*)(Bb + physB[r]);
    }
    cb = (cb == 2) ? 0 : cb + 1;
    asm volatile("s_waitcnt lgkmcnt(0)" ::: "memory");
    __builtin_amdgcn_sched_barrier(0);
    __builtin_amdgcn_s_setprio(1);
#pragma unroll
    for (int r = 0; r < 4; ++r)
#pragma unroll
      for (int f = 0; f < 4; ++f)
        acc[r][f] = __builtin_amdgcn_mfma_f32_16x16x32_bf16(am[r], bn[f], acc[r][f], 0, 0, 0);
    __builtin_amdgcn_s_setprio(0);
    if (tt + 2 < NT) asm volatile("s_waitcnt vmcnt(4)" ::: "memory");
    else             asm volatile("s_waitcnt vmcnt(0)" ::: "memory");
    __builtin_amdgcn_s_barrier();
  }

  // epilogue: n = token (col = lane&15), m = feature ((lane>>4)*4 + j)
  int lr = lane & 15, lg4 = (lane >> 4) * 4;
#pragma unroll
  for (int f = 0; f < 4; ++f) {
    int tokl = bx * 128 + nbase + f * 16 + lr;
    if (tokl >= ne) continue;
    size_t grow = (size_t)(off + tokl);
    if (EPI == 0) {
#pragma unroll
      for (int r = 0; r < 4; ++r) {
        ushort4 o;
        o.x = f2bf(gelu_fast(acc[r][f][0]));
        o.y = f2bf(gelu_fast(acc[r][f][1]));
        o.z = f2bf(gelu_fast(acc[r][f][2]));
        o.w = f2bf(gelu_fast(acc[r][f][3]));
        *(ushort4*)(Hout + grow * NOUT + f0 + mbase + r * 16 + lg4) = o;
      }
    } else {
      float w = pair_w[grow];
#pragma unroll
      for (int r = 0; r < 4; ++r) {
        float4 o;
        o.x = acc[r][f][0] * w; o.y = acc[r][f][1] * w;
        o.z = acc[r][f][2] * w; o.w = acc[r][f][3] * w;
        *(float4*)(Cout + grow * NOUT + f0 + mbase + r * 16 + lg4) = o;
      }
    }
  }
}

// ---------------------------------------------------------------------------
// Combine: out[token] = pair_out[p0] + pair_out[p1]
// ---------------------------------------------------------------------------
__global__ void combine(const float* __restrict__ pair_out, const int* __restrict__ pair_idx,
                        float* __restrict__ out) {
  int t = blockIdx.x;
  int p0 = pair_idx[t*2], p1 = pair_idx[t*2+1];
  int c = threadIdx.x * 4;
  float4 a = *(const float4*)(pair_out + (size_t)p0 * D_ + c);
  float4 b = *(const float4*)(pair_out + (size_t)p1 * D_ + c);
  float4 o; o.x = a.x + b.x; o.y = a.y + b.y; o.z = a.z + b.z; o.w = a.w + b.w;
  *(float4*)(out + (size_t)t * D_ + c) = o;
}

// ---------------------------------------------------------------------------
// Workspace layout (bytes) — requires ~210 MiB of d_ws.
// ---------------------------------------------------------------------------
extern "C" void kernel_launch(void* const* d_in, const int* in_sizes, int n_in,
                              void* d_out, int out_size, void* d_ws, size_t ws_size,
                              hipStream_t stream) {
  const float* inputs      = (const float*)d_in[0];
  const float* task_param  = (const float*)d_in[1];
  const float* gate_img_w  = (const float*)d_in[2];
  const float* gate_img_b  = (const float*)d_in[3];
  const float* gate_txt_w  = (const float*)d_in[4];
  const float* gate_txt_b  = (const float*)d_in[5];
  const float* task_gate_w = (const float*)d_in[6];
  const float* task_gate_b = (const float*)d_in[7];
  const float* alpha       = (const float*)d_in[8];
  const float* w1          = (const float*)d_in[9];
  const float* w2          = (const float*)d_in[10];
  const int*   is_text     = (const int*)d_in[11];
  float* out = (float*)d_out;

  char* ws = (char*)d_ws;
  u16* w1b = (u16*)(ws + 0);
  u16* w2b = (u16*)(ws + 67108864);
  u16* Xg  = (u16*)(ws + 134217728);
  u16* Hb  = (u16*)(ws + 151257088);
  float4* sel_w   = (float4*)(ws + 219414528);
  float* pair_w   = (float*)(ws + 219480064);
  int* pair_idx   = (int*)(ws + 219513344);
  float* prob_part= (float*)(ws + 219546112);
  int* count_part = (int*)(ws + 219578880);
  int* counters   = (int*)(ws + 219611648);
  float* pair_out = (float*)(ws + 0);  // aliases w1b (dead after GEMM1)

  int* counts  = counters;
  int* offs    = counters + 8;
  int* cursors = counters + 16;

  convtrans<D_, H_><<<dim3(H_/64, D_/64, E_), 256, 0, stream>>>(w1, w1b);
  convtrans<H_, D_><<<dim3(D_/64, H_/64, E_), 256, 0, stream>>>(w2, w2b);
  gating<<<dim3(T_/4), 256, 0, stream>>>(inputs, task_param, gate_img_w, gate_img_b,
      gate_txt_w, gate_txt_b, task_gate_w, task_gate_b, alpha, is_text,
      sel_w, prob_part, count_part);
  finalize<<<dim3(1), 256, 0, stream>>>(prob_part, count_part, counts, offs, cursors,
      out + (size_t)T_ * D_);
  scatter_gather<<<dim3(T_/4), 256, 0, stream>>>(inputs, sel_w, cursors, pair_w, pair_idx, Xg);
  // GEMM1: Tok=Xg (K=1024), Wt=w1b [E][H][D] -> H (feature tiles over H=4096)
  gemm_ffn<0, D_, H_><<<dim3(32, H_/128, E_), 256, 0, stream>>>(
      Xg, w1b, counts, offs, pair_w, Hb, (float*)nullptr);
  // GEMM2: Tok=Hb (K=4096), Wt=w2b [E][D][H] -> D (feature tiles over D=1024)
  gemm_ffn<1, H_, D_><<<dim3(32, D_/128, E_), 256, 0, stream>>>(
      Hb, w2b, counts, offs, pair_w, (u16*)nullptr, pair_out);
  combine<<<dim3(T_), 256, 0, stream>>>(pair_out, pair_idx, out);
}

// Round 4
// 704.681 us; speedup vs baseline: 1.7781x; 1.3597x over previous
//
#include <hip/hip_runtime.h>
#include <hip/hip_bf16.h>
#include <math.h>

// Problem constants
#define L_ 1024
#define B_ 4
#define D_ 1024
#define E_ 8
#define K_ 2
#define H_ 4096
#define T_ (L_*B_)        // 4096 tokens
#define P_ (T_*K_)        // 8192 token-expert pairs
#define PPAD (P_+128)     // padded rows so partial GEMM tiles can over-read safely

typedef unsigned short u16;
typedef __attribute__((ext_vector_type(4))) float f32x4;
typedef __attribute__((ext_vector_type(8))) short s16x8;

__device__ __forceinline__ u16 f2bf(float f) {
  uint32_t u = __float_as_uint(f);
  uint32_t r = (u + 0x7FFFu + ((u >> 16) & 1u)) >> 16;  // RNE
  return (u16)r;
}
// gelu tanh-approx in sigmoid form: 0.5v(1+tanh(c(v+0.044715v^3))) = v*sigma(2c*u)
__device__ __forceinline__ float gelu_fast(float v) {
  float u = v * (1.0f + 0.044715f * v * v);
  float t = __expf(-1.5957691216057308f * u);   // 2*0.7978845608...
  return v / (1.0f + t);
}

// ---------------------------------------------------------------------------
// fp32 [E][R][C] -> bf16 [E][C][R]  (transpose + convert, 64x64 LDS tiles)
// ---------------------------------------------------------------------------
template<int R, int C>
__global__ void convtrans(const float* __restrict__ in, u16* __restrict__ out) {
  __shared__ float tile[64][65];
  int e = blockIdx.z;
  int r0 = blockIdx.y * 64, c0 = blockIdx.x * 64;
  const float* src = in + (size_t)e * R * C;
  u16* dst = out + (size_t)e * R * C;
  int t = threadIdx.x;
  int tr = t >> 4, tc = (t & 15) * 4;
#pragma unroll
  for (int p = 0; p < 4; ++p) {
    int r = tr + p * 16;
    float4 v = *(const float4*)(src + (size_t)(r0 + r) * C + c0 + tc);
    tile[r][tc] = v.x; tile[r][tc+1] = v.y; tile[r][tc+2] = v.z; tile[r][tc+3] = v.w;
  }
  __syncthreads();
#pragma unroll
  for (int p = 0; p < 4; ++p) {
    int c = tr + p * 16;
    ushort4 o;
    o.x = f2bf(tile[tc+0][c]); o.y = f2bf(tile[tc+1][c]);
    o.z = f2bf(tile[tc+2][c]); o.w = f2bf(tile[tc+3][c]);
    *(ushort4*)(dst + (size_t)(c0 + c) * R + r0 + tc) = o;
  }
}

// ---------------------------------------------------------------------------
// Gating: one wave per token. fp32 logits (must match reference top-k).
// ---------------------------------------------------------------------------
__global__ void gating(const float* __restrict__ x, const float* __restrict__ task_param,
                       const float* __restrict__ gw_img, const float* __restrict__ gb_img,
                       const float* __restrict__ gw_txt, const float* __restrict__ gb_txt,
                       const float* __restrict__ tgw, const float* __restrict__ tgb,
                       const float* __restrict__ alpha_p, const int* __restrict__ is_text_p,
                       float4* __restrict__ sel_w, float* __restrict__ prob_part,
                       int* __restrict__ count_part) {
  __shared__ float wprob[4][8];
  __shared__ int wcnt[4][8];
  int wid = threadIdx.x >> 6, lane = threadIdx.x & 63;
  int t = blockIdx.x * 4 + wid;
  int b = t & (B_ - 1);
  int it = is_text_p[0];
  const float* gw = it ? gw_txt : gw_img;
  const float* gb = it ? gb_txt : gb_img;
  float alpha = alpha_p[0];
  const float* xr = x + (size_t)t * D_;
  const float* tp = task_param + (size_t)b * D_;
  float acc[8] = {0,0,0,0,0,0,0,0};
  float tac[8] = {0,0,0,0,0,0,0,0};
  for (int i = 0; i < D_/64; ++i) {
    int d = i * 64 + lane;
    float xv = xr[d], tv = tp[d];
#pragma unroll
    for (int e = 0; e < 8; ++e) {
      acc[e] += xv * gw[d*8 + e];
      tac[e] += tv * tgw[d*8 + e];
    }
  }
#pragma unroll
  for (int e = 0; e < 8; ++e) {
#pragma unroll
    for (int off = 32; off > 0; off >>= 1) {
      acc[e] += __shfl_xor(acc[e], off);
      tac[e] += __shfl_xor(tac[e], off);
    }
  }
  float lg[8];
#pragma unroll
  for (int e = 0; e < 8; ++e)
    lg[e] = (1.0f - alpha) * (acc[e] + gb[e]) + alpha * (tac[e] + tgb[e]);
  // full softmax (for l_aux)
  float m = lg[0];
#pragma unroll
  for (int e = 1; e < 8; ++e) m = fmaxf(m, lg[e]);
  float pr[8], ps = 0.f;
#pragma unroll
  for (int e = 0; e < 8; ++e) { pr[e] = expf(lg[e] - m); ps += pr[e]; }
  float inv = 1.0f / ps;
  // top-2 (ties -> lowest index, matching lax.top_k)
  int i0 = 0; float v0 = lg[0];
#pragma unroll
  for (int e = 1; e < 8; ++e) if (lg[e] > v0) { v0 = lg[e]; i0 = e; }
  int i1 = -1; float v1 = -1e30f;
#pragma unroll
  for (int e = 0; e < 8; ++e) if (e != i0 && lg[e] > v1) { v1 = lg[e]; i1 = e; }
  float ex = expf(v1 - v0);
  float w0 = 1.0f / (1.0f + ex), w1 = ex / (1.0f + ex);
  if (lane == 0) {
    sel_w[t] = make_float4(__int_as_float(i0), __int_as_float(i1), w0, w1);
#pragma unroll
    for (int e = 0; e < 8; ++e) {
      wprob[wid][e] = pr[e] * inv;
      wcnt[wid][e] = (i0 == e) + (i1 == e);
    }
  }
  __syncthreads();
  if (threadIdx.x < 8) {
    int e = threadIdx.x;
    prob_part[blockIdx.x * 8 + e] = wprob[0][e] + wprob[1][e] + wprob[2][e] + wprob[3][e];
    count_part[blockIdx.x * 8 + e] = wcnt[0][e] + wcnt[1][e] + wcnt[2][e] + wcnt[3][e];
  }
}

// ---------------------------------------------------------------------------
// Finalize: deterministic reduce of partials -> counts/offsets/cursors + l_aux
// ---------------------------------------------------------------------------
__global__ void finalize(const float* __restrict__ prob_part, const int* __restrict__ count_part,
                         int* __restrict__ counts, int* __restrict__ offs,
                         int* __restrict__ cursors, float* __restrict__ laux_out) {
  __shared__ float ps_[256];
  __shared__ int cs_[256];
  int t = threadIdx.x;
  int e = t & 7, s = t >> 3;  // 32 strided chunks per expert
  float p = 0.f; int c = 0;
  for (int b = s; b < 1024; b += 32) { p += prob_part[b*8 + e]; c += count_part[b*8 + e]; }
  ps_[t] = p; cs_[t] = c;
  __syncthreads();
  for (int st = 16; st > 0; st >>= 1) {
    if (s < st) { ps_[t] += ps_[t + st*8]; cs_[t] += cs_[t + st*8]; }
    __syncthreads();
  }
  if (t == 0) {
    int off = 0; float laux = 0.f;
    for (int ee = 0; ee < 8; ++ee) {
      int cnt = cs_[ee];
      counts[ee] = cnt; offs[ee] = off; cursors[ee] = off; off += cnt;
      laux += (ps_[ee] * (1.0f/4096.0f)) * ((float)cnt * (1.0f/4096.0f));
    }
    *laux_out = laux;
  }
}

// ---------------------------------------------------------------------------
// Scatter + gather: assign bucket slots, record token->pair map, gather bf16 rows
// ---------------------------------------------------------------------------
__global__ void scatter_gather(const float* __restrict__ x, const float4* __restrict__ sel_w,
                               int* __restrict__ cursors, float* __restrict__ pair_w,
                               int* __restrict__ pair_idx, u16* __restrict__ Xg) {
  int wid = threadIdx.x >> 6, lane = threadIdx.x & 63;
  int t = blockIdx.x * 4 + wid;
  float4 sw = sel_w[t];
  int s0 = __float_as_int(sw.x), s1 = __float_as_int(sw.y);
  int p0 = 0, p1 = 0;
  if (lane == 0) {
    p0 = atomicAdd(&cursors[s0], 1);
    p1 = atomicAdd(&cursors[s1], 1);
  }
  p0 = __shfl(p0, 0); p1 = __shfl(p1, 0);
  if (lane == 0) {
    pair_w[p0] = sw.z; pair_w[p1] = sw.w;
    pair_idx[t*2] = p0; pair_idx[t*2+1] = p1;
  }
  const float* xr = x + (size_t)t * D_;
  u16* d0 = Xg + (size_t)p0 * D_;
  u16* d1 = Xg + (size_t)p1 * D_;
#pragma unroll
  for (int i = 0; i < 4; ++i) {
    int c = i * 256 + lane * 4;
    float4 v = *(const float4*)(xr + c);
    ushort4 o;
    o.x = f2bf(v.x); o.y = f2bf(v.y); o.z = f2bf(v.z); o.w = f2bf(v.w);
    *(ushort4*)(d0 + c) = o;
    *(ushort4*)(d1 + c) = o;
  }
}

// ---------------------------------------------------------------------------
// Grouped GEMM. bf16 MFMA 16x16x32, tile 128(feature) x 128(token), BK=32.
// Structure: T3-minimum 2-phase double-buffer, __syncthreads only (compiler
// manages all waitcnts — m97-proven), no inline asm.
//
// XCD-affinity 1-D grid: gid%8 = expert  (XCD = blockIdx%8 heuristic), so
// each expert's whole working set lives on one XCD's L2: tokens (2MB) stay
// resident; each weight panel is fetched from HBM ~once. Within an XCD,
// j-inner (GEMM1) makes one panel's token tiles consecutive.
//
// LDS swizzle (both-sides involution, rule 21, verified R3): logical 16B
// slot q lives at physical slot q^((q>>3)&3). Staging dest is linear
// (lane s -> slot s); global source carries the permutation (coalescing
// preserved: permuted-contiguous sets). Fragment reads apply the same XOR:
// 2-way bank aliasing only (free). SQ_LDS_BANK_CONFLICT == 0 in R3.
//
// Operand roles: A(m)=weight rows [feature][K], B(n)=token rows. acc j-index
// walks consecutive features -> vectorized epilogue.
// EPI==0: Hout[tok][h] = bf16(gelu(acc))   EPI==1: Cout[tok][d] = acc*pair_w
// ---------------------------------------------------------------------------
template<int EPI, int KDIM, int NOUT, int BYINNER>
__global__ __launch_bounds__(256)
void gemm_ffn(const u16* __restrict__ Tok, const u16* __restrict__ Wt,
              const int* __restrict__ counts, const int* __restrict__ offs,
              const float* __restrict__ pair_w,
              u16* __restrict__ Hout, float* __restrict__ Cout) {
  constexpr int NTK = 16;            // token-tile slots (grid-stride covers more)
  constexpr int NPL = NOUT / 128;    // feature panels per expert
  int gid = blockIdx.x;
  int e = gid & 7;                   // XCD affinity: expert == gid%8
  int idx = gid >> 3;
  int by, j0;
  if (BYINNER) { by = idx & (NPL - 1); j0 = idx / NPL; }
  else         { by = idx / NTK;       j0 = idx & (NTK - 1); }
  int ne = counts[e];
  int off = offs[e];
  int f0 = by * 128;
  __shared__ u16 As[2][4096];        // weight tile buffers (8KB each)
  __shared__ u16 Bs[2][4096];        // token tile buffers
  int t = threadIdx.x, lane = t & 63, wid = t >> 6;
  const u16* Wg = Wt + (size_t)e * NOUT * KDIM + (size_t)f0 * KDIM;

  // staging map (slot -> global row/k via involution), verified in R3
  const u16* pW[2]; int srow[2], skk[2], ldd[2];
#pragma unroll
  for (int i = 0; i < 2; ++i) {
    int slot = i * 256 + wid * 64 + lane;
    int ls = slot ^ ((slot >> 3) & 3);
    srow[i] = ls >> 2; skk[i] = (ls & 3) << 3;
    pW[i] = Wg + (size_t)srow[i] * KDIM + skk[i];
    ldd[i] = slot * 8;               // u16 index into tile
  }

  // fragment read offsets (u16 index), same involution
  int mbase = (wid >> 1) * 64, nbase = (wid & 1) * 64;
  int physA[4], physB[4];
#pragma unroll
  for (int r = 0; r < 4; ++r) {
    int rowm = mbase + r * 16 + (lane & 15);
    int s1 = rowm * 4 + (lane >> 4);
    physA[r] = (s1 ^ ((s1 >> 3) & 3)) * 8;
    int rown = nbase + r * 16 + (lane & 15);
    int s2 = rown * 4 + (lane >> 4);
    physB[r] = (s2 ^ ((s2 >> 3) & 3)) * 8;
  }

  constexpr int NT = KDIM / 32;
  int lr = lane & 15, lg4 = (lane >> 4) * 4;

  for (int bx = j0; bx * 128 < ne; bx += NTK) {
    const u16* Tg = Tok + (size_t)(off + bx * 128) * KDIM;
    f32x4 acc[4][4] = {};
    // prologue: stage tile 0 into buf 0
#pragma unroll
    for (int i = 0; i < 2; ++i) {
      __builtin_amdgcn_global_load_lds(
          (const __attribute__((address_space(1))) void*)(pW[i]),
          (__attribute__((address_space(3))) void*)(&As[0][ldd[i]]), 16, 0, 0);
      __builtin_amdgcn_global_load_lds(
          (const __attribute__((address_space(1))) void*)(Tg + (size_t)srow[i] * KDIM + skk[i]),
          (__attribute__((address_space(3))) void*)(&Bs[0][ldd[i]]), 16, 0, 0);
    }
    __syncthreads();
    int cur = 0;
    for (int tt = 0; tt < NT; ++tt) {
      if (tt + 1 < NT) {
        int k0 = (tt + 1) * 32;
        int nb = cur ^ 1;
#pragma unroll
        for (int i = 0; i < 2; ++i) {
          __builtin_amdgcn_global_load_lds(
              (const __attribute__((address_space(1))) void*)(pW[i] + k0),
              (__attribute__((address_space(3))) void*)(&As[nb][ldd[i]]), 16, 0, 0);
          __builtin_amdgcn_global_load_lds(
              (const __attribute__((address_space(1))) void*)(Tg + (size_t)srow[i] * KDIM + skk[i] + k0),
              (__attribute__((address_space(3))) void*)(&Bs[nb][ldd[i]]), 16, 0, 0);
        }
      }
      const u16* Ab = &As[cur][0]; const u16* Bb = &Bs[cur][0];
      s16x8 am[4], bn[4];
#pragma unroll
      for (int r = 0; r < 4; ++r) {
        am[r] = *(const s16x8*)(Ab + physA[r]);
        bn[r] = *(const s16x8*)(Bb + physB[r]);
      }
#pragma unroll
      for (int r = 0; r < 4; ++r)
#pragma unroll
        for (int f = 0; f < 4; ++f)
          acc[r][f] = __builtin_amdgcn_mfma_f32_16x16x32_bf16(am[r], bn[f], acc[r][f], 0, 0, 0);
      __syncthreads();   // drains vmcnt(0)+lgkmcnt(0): prefetch issued above
                         // overlapped with this tile's ds_read+MFMA
      cur ^= 1;
    }

    // epilogue: n = token (col = lane&15), m = feature ((lane>>4)*4 + j)
#pragma unroll
    for (int f = 0; f < 4; ++f) {
      int tokl = bx * 128 + nbase + f * 16 + lr;
      if (tokl >= ne) continue;
      size_t grow = (size_t)(off + tokl);
      if (EPI == 0) {
#pragma unroll
        for (int r = 0; r < 4; ++r) {
          ushort4 o;
          o.x = f2bf(gelu_fast(acc[r][f][0]));
          o.y = f2bf(gelu_fast(acc[r][f][1]));
          o.z = f2bf(gelu_fast(acc[r][f][2]));
          o.w = f2bf(gelu_fast(acc[r][f][3]));
          *(ushort4*)(Hout + grow * NOUT + f0 + mbase + r * 16 + lg4) = o;
        }
      } else {
        float w = pair_w[grow];
#pragma unroll
        for (int r = 0; r < 4; ++r) {
          float4 o;
          o.x = acc[r][f][0] * w; o.y = acc[r][f][1] * w;
          o.z = acc[r][f][2] * w; o.w = acc[r][f][3] * w;
          *(float4*)(Cout + grow * NOUT + f0 + mbase + r * 16 + lg4) = o;
        }
      }
    }
  }
}

// ---------------------------------------------------------------------------
// Combine: out[token] = pair_out[p0] + pair_out[p1]
// ---------------------------------------------------------------------------
__global__ void combine(const float* __restrict__ pair_out, const int* __restrict__ pair_idx,
                        float* __restrict__ out) {
  int t = blockIdx.x;
  int p0 = pair_idx[t*2], p1 = pair_idx[t*2+1];
  int c = threadIdx.x * 4;
  float4 a = *(const float4*)(pair_out + (size_t)p0 * D_ + c);
  float4 b = *(const float4*)(pair_out + (size_t)p1 * D_ + c);
  float4 o; o.x = a.x + b.x; o.y = a.y + b.y; o.z = a.z + b.z; o.w = a.w + b.w;
  *(float4*)(out + (size_t)t * D_ + c) = o;
}

// ---------------------------------------------------------------------------
// Workspace layout (bytes) — requires ~210 MiB of d_ws.
// ---------------------------------------------------------------------------
extern "C" void kernel_launch(void* const* d_in, const int* in_sizes, int n_in,
                              void* d_out, int out_size, void* d_ws, size_t ws_size,
                              hipStream_t stream) {
  const float* inputs      = (const float*)d_in[0];
  const float* task_param  = (const float*)d_in[1];
  const float* gate_img_w  = (const float*)d_in[2];
  const float* gate_img_b  = (const float*)d_in[3];
  const float* gate_txt_w  = (const float*)d_in[4];
  const float* gate_txt_b  = (const float*)d_in[5];
  const float* task_gate_w = (const float*)d_in[6];
  const float* task_gate_b = (const float*)d_in[7];
  const float* alpha       = (const float*)d_in[8];
  const float* w1          = (const float*)d_in[9];
  const float* w2          = (const float*)d_in[10];
  const int*   is_text     = (const int*)d_in[11];
  float* out = (float*)d_out;

  char* ws = (char*)d_ws;
  u16* w1b = (u16*)(ws + 0);
  u16* w2b = (u16*)(ws + 67108864);
  u16* Xg  = (u16*)(ws + 134217728);
  u16* Hb  = (u16*)(ws + 151257088);
  float4* sel_w   = (float4*)(ws + 219414528);
  float* pair_w   = (float*)(ws + 219480064);
  int* pair_idx   = (int*)(ws + 219513344);
  float* prob_part= (float*)(ws + 219546112);
  int* count_part = (int*)(ws + 219578880);
  int* counters   = (int*)(ws + 219611648);
  float* pair_out = (float*)(ws + 0);  // aliases w1b (dead after GEMM1)

  int* counts  = counters;
  int* offs    = counters + 8;
  int* cursors = counters + 16;

  convtrans<D_, H_><<<dim3(H_/64, D_/64, E_), 256, 0, stream>>>(w1, w1b);
  convtrans<H_, D_><<<dim3(D_/64, H_/64, E_), 256, 0, stream>>>(w2, w2b);
  gating<<<dim3(T_/4), 256, 0, stream>>>(inputs, task_param, gate_img_w, gate_img_b,
      gate_txt_w, gate_txt_b, task_gate_w, task_gate_b, alpha, is_text,
      sel_w, prob_part, count_part);
  finalize<<<dim3(1), 256, 0, stream>>>(prob_part, count_part, counts, offs, cursors,
      out + (size_t)T_ * D_);
  scatter_gather<<<dim3(T_/4), 256, 0, stream>>>(inputs, sel_w, cursors, pair_w, pair_idx, Xg);
  // GEMM1: 1-D grid, gid%8=expert, j-inner. 8e x 32by x 16j = 4096 blocks.
  gemm_ffn<0, D_, H_, 0><<<dim3(4096), 256, 0, stream>>>(
      Xg, w1b, counts, offs, pair_w, Hb, (float*)nullptr);
  // GEMM2: 1-D grid, gid%8=expert, by-inner. 8e x 8by x 16j = 1024 blocks.
  gemm_ffn<1, H_, D_, 1><<<dim3(1024), 256, 0, stream>>>(
      Hb, w2b, counts, offs, pair_w, (u16*)nullptr, pair_out);
  combine<<<dim3(T_), 256, 0, stream>>>(pair_out, pair_idx, out);
}

// Round 5
// 512.473 us; speedup vs baseline: 2.4450x; 1.3751x over previous
//
#include <hip/hip_runtime.h>
#include <hip/hip_bf16.h>
#include <math.h>

// Problem constants
#define L_ 1024
#define B_ 4
#define D_ 1024
#define E_ 8
#define K_ 2
#define H_ 4096
#define T_ (L_*B_)        // 4096 tokens
#define P_ (T_*K_)        // 8192 token-expert pairs
#define PPAD (P_+256)     // padded rows so partial 256-tiles can over-read safely

typedef unsigned short u16;
typedef __attribute__((ext_vector_type(4))) float f32x4;
typedef __attribute__((ext_vector_type(8))) short s16x8;

__device__ __forceinline__ u16 f2bf(float f) {
  uint32_t u = __float_as_uint(f);
  uint32_t r = (u + 0x7FFFu + ((u >> 16) & 1u)) >> 16;  // RNE
  return (u16)r;
}
// gelu tanh-approx in sigmoid form
__device__ __forceinline__ float gelu_fast(float v) {
  float u = v * (1.0f + 0.044715f * v * v);
  float t = __expf(-1.5957691216057308f * u);
  return v / (1.0f + t);
}

// ---------------------------------------------------------------------------
// fp32 [E][R][C] -> bf16 [E][C][R]  (transpose + convert, 64x64 LDS tiles)
// ---------------------------------------------------------------------------
template<int R, int C>
__global__ void convtrans(const float* __restrict__ in, u16* __restrict__ out) {
  __shared__ float tile[64][65];
  int e = blockIdx.z;
  int r0 = blockIdx.y * 64, c0 = blockIdx.x * 64;
  const float* src = in + (size_t)e * R * C;
  u16* dst = out + (size_t)e * R * C;
  int t = threadIdx.x;
  int tr = t >> 4, tc = (t & 15) * 4;
#pragma unroll
  for (int p = 0; p < 4; ++p) {
    int r = tr + p * 16;
    float4 v = *(const float4*)(src + (size_t)(r0 + r) * C + c0 + tc);
    tile[r][tc] = v.x; tile[r][tc+1] = v.y; tile[r][tc+2] = v.z; tile[r][tc+3] = v.w;
  }
  __syncthreads();
#pragma unroll
  for (int p = 0; p < 4; ++p) {
    int c = tr + p * 16;
    ushort4 o;
    o.x = f2bf(tile[tc+0][c]); o.y = f2bf(tile[tc+1][c]);
    o.z = f2bf(tile[tc+2][c]); o.w = f2bf(tile[tc+3][c]);
    *(ushort4*)(dst + (size_t)(c0 + c) * R + r0 + tc) = o;
  }
}

// ---------------------------------------------------------------------------
// Gating: one wave per token. fp32 logits (must match reference top-k).
// ---------------------------------------------------------------------------
__global__ void gating(const float* __restrict__ x, const float* __restrict__ task_param,
                       const float* __restrict__ gw_img, const float* __restrict__ gb_img,
                       const float* __restrict__ gw_txt, const float* __restrict__ gb_txt,
                       const float* __restrict__ tgw, const float* __restrict__ tgb,
                       const float* __restrict__ alpha_p, const int* __restrict__ is_text_p,
                       float4* __restrict__ sel_w, float* __restrict__ prob_part,
                       int* __restrict__ count_part) {
  __shared__ float wprob[4][8];
  __shared__ int wcnt[4][8];
  int wid = threadIdx.x >> 6, lane = threadIdx.x & 63;
  int t = blockIdx.x * 4 + wid;
  int b = t & (B_ - 1);
  int it = is_text_p[0];
  const float* gw = it ? gw_txt : gw_img;
  const float* gb = it ? gb_txt : gb_img;
  float alpha = alpha_p[0];
  const float* xr = x + (size_t)t * D_;
  const float* tp = task_param + (size_t)b * D_;
  float acc[8] = {0,0,0,0,0,0,0,0};
  float tac[8] = {0,0,0,0,0,0,0,0};
  for (int i = 0; i < D_/64; ++i) {
    int d = i * 64 + lane;
    float xv = xr[d], tv = tp[d];
#pragma unroll
    for (int e = 0; e < 8; ++e) {
      acc[e] += xv * gw[d*8 + e];
      tac[e] += tv * tgw[d*8 + e];
    }
  }
#pragma unroll
  for (int e = 0; e < 8; ++e) {
#pragma unroll
    for (int off = 32; off > 0; off >>= 1) {
      acc[e] += __shfl_xor(acc[e], off);
      tac[e] += __shfl_xor(tac[e], off);
    }
  }
  float lg[8];
#pragma unroll
  for (int e = 0; e < 8; ++e)
    lg[e] = (1.0f - alpha) * (acc[e] + gb[e]) + alpha * (tac[e] + tgb[e]);
  float m = lg[0];
#pragma unroll
  for (int e = 1; e < 8; ++e) m = fmaxf(m, lg[e]);
  float pr[8], ps = 0.f;
#pragma unroll
  for (int e = 0; e < 8; ++e) { pr[e] = expf(lg[e] - m); ps += pr[e]; }
  float inv = 1.0f / ps;
  int i0 = 0; float v0 = lg[0];
#pragma unroll
  for (int e = 1; e < 8; ++e) if (lg[e] > v0) { v0 = lg[e]; i0 = e; }
  int i1 = -1; float v1 = -1e30f;
#pragma unroll
  for (int e = 0; e < 8; ++e) if (e != i0 && lg[e] > v1) { v1 = lg[e]; i1 = e; }
  float ex = expf(v1 - v0);
  float w0 = 1.0f / (1.0f + ex), w1 = ex / (1.0f + ex);
  if (lane == 0) {
    sel_w[t] = make_float4(__int_as_float(i0), __int_as_float(i1), w0, w1);
#pragma unroll
    for (int e = 0; e < 8; ++e) {
      wprob[wid][e] = pr[e] * inv;
      wcnt[wid][e] = (i0 == e) + (i1 == e);
    }
  }
  __syncthreads();
  if (threadIdx.x < 8) {
    int e = threadIdx.x;
    prob_part[blockIdx.x * 8 + e] = wprob[0][e] + wprob[1][e] + wprob[2][e] + wprob[3][e];
    count_part[blockIdx.x * 8 + e] = wcnt[0][e] + wcnt[1][e] + wcnt[2][e] + wcnt[3][e];
  }
}

// ---------------------------------------------------------------------------
// Finalize: deterministic reduce of partials -> counts/offsets/cursors + l_aux
// ---------------------------------------------------------------------------
__global__ void finalize(const float* __restrict__ prob_part, const int* __restrict__ count_part,
                         int* __restrict__ counts, int* __restrict__ offs,
                         int* __restrict__ cursors, float* __restrict__ laux_out) {
  __shared__ float ps_[256];
  __shared__ int cs_[256];
  int t = threadIdx.x;
  int e = t & 7, s = t >> 3;
  float p = 0.f; int c = 0;
  for (int b = s; b < 1024; b += 32) { p += prob_part[b*8 + e]; c += count_part[b*8 + e]; }
  ps_[t] = p; cs_[t] = c;
  __syncthreads();
  for (int st = 16; st > 0; st >>= 1) {
    if (s < st) { ps_[t] += ps_[t + st*8]; cs_[t] += cs_[t + st*8]; }
    __syncthreads();
  }
  if (t == 0) {
    int off = 0; float laux = 0.f;
    for (int ee = 0; ee < 8; ++ee) {
      int cnt = cs_[ee];
      counts[ee] = cnt; offs[ee] = off; cursors[ee] = off; off += cnt;
      laux += (ps_[ee] * (1.0f/4096.0f)) * ((float)cnt * (1.0f/4096.0f));
    }
    *laux_out = laux;
  }
}

// ---------------------------------------------------------------------------
// Scatter + gather: assign bucket slots, record token->pair map, gather bf16 rows
// ---------------------------------------------------------------------------
__global__ void scatter_gather(const float* __restrict__ x, const float4* __restrict__ sel_w,
                               int* __restrict__ cursors, float* __restrict__ pair_w,
                               int* __restrict__ pair_idx, u16* __restrict__ Xg) {
  int wid = threadIdx.x >> 6, lane = threadIdx.x & 63;
  int t = blockIdx.x * 4 + wid;
  float4 sw = sel_w[t];
  int s0 = __float_as_int(sw.x), s1 = __float_as_int(sw.y);
  int p0 = 0, p1 = 0;
  if (lane == 0) {
    p0 = atomicAdd(&cursors[s0], 1);
    p1 = atomicAdd(&cursors[s1], 1);
  }
  p0 = __shfl(p0, 0); p1 = __shfl(p1, 0);
  if (lane == 0) {
    pair_w[p0] = sw.z; pair_w[p1] = sw.w;
    pair_idx[t*2] = p0; pair_idx[t*2+1] = p1;
  }
  const float* xr = x + (size_t)t * D_;
  u16* d0 = Xg + (size_t)p0 * D_;
  u16* d1 = Xg + (size_t)p1 * D_;
#pragma unroll
  for (int i = 0; i < 4; ++i) {
    int c = i * 256 + lane * 4;
    float4 v = *(const float4*)(xr + c);
    ushort4 o;
    o.x = f2bf(v.x); o.y = f2bf(v.y); o.z = f2bf(v.z); o.w = f2bf(v.w);
    *(ushort4*)(d0 + c) = o;
    *(ushort4*)(d1 + c) = o;
  }
}

// ---------------------------------------------------------------------------
// Grouped GEMM, 256x256 tile, BK=64, 8 waves (512 thr), 2-phase double-buffer
// (T3-minimum recipe: issue STAGE before ds_read+MFMA, one barrier per K-tile,
// compiler-managed waitcnts). 128 KB LDS -> 1 block/CU.
//
// Per-iter arithmetic: 64 KB from L2, 512 MFMAs (8.4 MFLOP) -> AI=128 FLOP/B;
// per-CU L2 BW no longer binds (needs ~76 GB/s of 135 GB/s at full MFMA).
//
// LDS swizzle: row = 8 x 16B slots (BK=64). phys_slot = row*8 + (kk ^ (row&7)).
// Involution; staging dest stays LINEAR in thread id (global_load_lds rule),
// global source address carries the permutation (within an 8-lane run the
// row is fixed and kk is permuted -> full 128B coalescing). Fragment
// ds_read_b128: 16 lanes reading 16 consecutive rows at fixed kk spread over
// all 8 slot positions -> 2-way bank aliasing only (free, m136).
//
// Roles: A(m)=weights(features), B(n)=tokens. acc reg j walks 4 consecutive
// features -> vectorized stores. Wave grid: wf=wid&1 (2x128 feat), wt=wid>>1
// (4x64 tok). Per wave: 8 A-frags x 4 B-frags, acc = 128 VGPRs.
//
// KSPLIT: block covers k in [ks*KLEN, (ks+1)*KLEN); EPI==1 writes to
// Cout + ks*P_*D_ (disjoint part buffers, summed in combine; deterministic).
// Grid: 8(expert=gid&7, XCD affinity) x NPANEL x KSPLIT x JSLOTS = 256.
// ---------------------------------------------------------------------------
template<int EPI, int KDIM, int KLEN, int NOUT, int NPANEL, int KSPLIT, int JSLOTS>
__global__ __launch_bounds__(512, 2)
void gemm256(const u16* __restrict__ Tok, const u16* __restrict__ Wt,
             const int* __restrict__ counts, const int* __restrict__ offs,
             const float* __restrict__ pair_w,
             u16* __restrict__ Hout, float* __restrict__ Cout) {
  int gid = blockIdx.x;
  int e = gid & 7;
  int idx = gid >> 3;
  int panel = idx % NPANEL; idx /= NPANEL;
  int ks = idx % KSPLIT;    idx /= KSPLIT;
  int j0 = idx;             // [0, JSLOTS)
  int ne = counts[e];
  int off = offs[e];
  int kbase = ks * KLEN;
  float* Cpart = Cout + (size_t)ks * P_ * D_;

  __shared__ u16 As[2][16384];   // 256 x 64 bf16 = 32 KB per buffer
  __shared__ u16 Bs[2][16384];
  int t = threadIdx.x, lane = t & 63, wid = t >> 6;
  int wf = wid & 1, wt = wid >> 1;

  const u16* Wg = Wt + (size_t)e * NOUT * KDIM + (size_t)panel * 256 * KDIM + kbase;

  // staging map: sweep i covers slots [i*512 + t]; row = slot>>3,
  // kk = (slot&7) ^ (row&7)  (inverse of the read-side swizzle).
  int rowoff[4]; int ldsoff[4];
#pragma unroll
  for (int i = 0; i < 4; ++i) {
    int slot = i * 512 + t;
    int row = slot >> 3;
    int kk = (slot & 7) ^ (row & 7);
    rowoff[i] = row * KDIM + kk * 8;   // u16 offset into (base + k0)
    ldsoff[i] = slot * 8;              // linear u16 LDS offset
  }

  // fragment read offsets (u16): phys = (row*8 + (kk ^ (row&7)))*8
  int aoff[8][2], boff[4][2];
#pragma unroll
  for (int r = 0; r < 8; ++r) {
    int row = wf * 128 + r * 16 + (lane & 15);
#pragma unroll
    for (int h = 0; h < 2; ++h) {
      int kk = h * 4 + (lane >> 4);
      aoff[r][h] = (row * 8 + (kk ^ (row & 7))) * 8;
    }
  }
#pragma unroll
  for (int f = 0; f < 4; ++f) {
    int row = wt * 64 + f * 16 + (lane & 15);
#pragma unroll
    for (int h = 0; h < 2; ++h) {
      int kk = h * 4 + (lane >> 4);
      boff[f][h] = (row * 8 + (kk ^ (row & 7))) * 8;
    }
  }

  constexpr int NT = KLEN / 64;
  int lr = lane & 15, lg4 = (lane >> 4) * 4;

  for (int bx = j0; bx * 256 < ne; bx += JSLOTS) {
    const u16* Tg = Tok + (size_t)(off + bx * 256) * KDIM + kbase;
    f32x4 acc[8][4] = {};
    // prologue: stage K-tile 0 into buf 0
#pragma unroll
    for (int i = 0; i < 4; ++i) {
      __builtin_amdgcn_global_load_lds(
          (const __attribute__((address_space(1))) void*)(Wg + rowoff[i]),
          (__attribute__((address_space(3))) void*)(&As[0][ldsoff[i]]), 16, 0, 0);
      __builtin_amdgcn_global_load_lds(
          (const __attribute__((address_space(1))) void*)(Tg + rowoff[i]),
          (__attribute__((address_space(3))) void*)(&Bs[0][ldsoff[i]]), 16, 0, 0);
    }
    __syncthreads();
    int cur = 0;
    for (int tt = 0; tt < NT; ++tt) {
      if (tt + 1 < NT) {
        int k0 = (tt + 1) * 64;
        int nb = cur ^ 1;
#pragma unroll
        for (int i = 0; i < 4; ++i) {
          __builtin_amdgcn_global_load_lds(
              (const __attribute__((address_space(1))) void*)(Wg + rowoff[i] + k0),
              (__attribute__((address_space(3))) void*)(&As[nb][ldsoff[i]]), 16, 0, 0);
          __builtin_amdgcn_global_load_lds(
              (const __attribute__((address_space(1))) void*)(Tg + rowoff[i] + k0),
              (__attribute__((address_space(3))) void*)(&Bs[nb][ldsoff[i]]), 16, 0, 0);
        }
      }
      const u16* Ab = &As[cur][0]; const u16* Bb = &Bs[cur][0];
#pragma unroll
      for (int h = 0; h < 2; ++h) {
        s16x8 a[8], b[4];
#pragma unroll
        for (int r = 0; r < 8; ++r) a[r] = *(const s16x8*)(Ab + aoff[r][h]);
#pragma unroll
        for (int f = 0; f < 4; ++f) b[f] = *(const s16x8*)(Bb + boff[f][h]);
#pragma unroll
        for (int r = 0; r < 8; ++r)
#pragma unroll
          for (int f = 0; f < 4; ++f)
            acc[r][f] = __builtin_amdgcn_mfma_f32_16x16x32_bf16(a[r], b[f], acc[r][f], 0, 0, 0);
      }
      __syncthreads();
      cur ^= 1;
    }

    // epilogue: token = wt*64 + f*16 + lr (col), feature = wf*128 + r*16 + lg4 + j
#pragma unroll
    for (int f = 0; f < 4; ++f) {
      int tokl = bx * 256 + wt * 64 + f * 16 + lr;
      if (tokl >= ne) continue;
      size_t grow = (size_t)(off + tokl);
      if (EPI == 0) {
#pragma unroll
        for (int r = 0; r < 8; ++r) {
          ushort4 o;
          o.x = f2bf(gelu_fast(acc[r][f][0]));
          o.y = f2bf(gelu_fast(acc[r][f][1]));
          o.z = f2bf(gelu_fast(acc[r][f][2]));
          o.w = f2bf(gelu_fast(acc[r][f][3]));
          *(ushort4*)(Hout + grow * NOUT + panel * 256 + wf * 128 + r * 16 + lg4) = o;
        }
      } else {
        float w = pair_w[grow];
#pragma unroll
        for (int r = 0; r < 8; ++r) {
          float4 o;
          o.x = acc[r][f][0] * w; o.y = acc[r][f][1] * w;
          o.z = acc[r][f][2] * w; o.w = acc[r][f][3] * w;
          *(float4*)(Cpart + grow * NOUT + panel * 256 + wf * 128 + r * 16 + lg4) = o;
        }
      }
    }
  }
}

// ---------------------------------------------------------------------------
// Combine: out[token] = sum over 2 pairs x 2 K-parts
// ---------------------------------------------------------------------------
__global__ void combine(const float* __restrict__ pair_out, const int* __restrict__ pair_idx,
                        float* __restrict__ out) {
  const float* part1 = pair_out + (size_t)P_ * D_;
  int t = blockIdx.x;
  int p0 = pair_idx[t*2], p1 = pair_idx[t*2+1];
  int c = threadIdx.x * 4;
  float4 a0 = *(const float4*)(pair_out + (size_t)p0 * D_ + c);
  float4 a1 = *(const float4*)(part1    + (size_t)p0 * D_ + c);
  float4 b0 = *(const float4*)(pair_out + (size_t)p1 * D_ + c);
  float4 b1 = *(const float4*)(part1    + (size_t)p1 * D_ + c);
  float4 o;
  o.x = (a0.x + a1.x) + (b0.x + b1.x);
  o.y = (a0.y + a1.y) + (b0.y + b1.y);
  o.z = (a0.z + a1.z) + (b0.z + b1.z);
  o.w = (a0.w + a1.w) + (b0.w + b1.w);
  *(float4*)(out + (size_t)t * D_ + c) = o;
}

// ---------------------------------------------------------------------------
// Workspace layout (bytes):
//   w1b  [E][H][D] bf16 @ 0           (67108864)  <- aliased by pair_out parts
//   w2b  [E][D][H] bf16 @ 67108864    (67108864)
//   Xg   [PPAD][D] bf16 @ 134217728   (17301504)
//   Hb   [PPAD][H] bf16 @ 151519232   (69206016)
//   sel_w    @ 220725248; pair_w @ +65536; pair_idx @ +98816; prob_part...
//   pair_out: 2 parts x [P_][D_] f32 @ 0 (2 x 33554432 = 67108864, fits w1b)
// ---------------------------------------------------------------------------
extern "C" void kernel_launch(void* const* d_in, const int* in_sizes, int n_in,
                              void* d_out, int out_size, void* d_ws, size_t ws_size,
                              hipStream_t stream) {
  const float* inputs      = (const float*)d_in[0];
  const float* task_param  = (const float*)d_in[1];
  const float* gate_img_w  = (const float*)d_in[2];
  const float* gate_img_b  = (const float*)d_in[3];
  const float* gate_txt_w  = (const float*)d_in[4];
  const float* gate_txt_b  = (const float*)d_in[5];
  const float* task_gate_w = (const float*)d_in[6];
  const float* task_gate_b = (const float*)d_in[7];
  const float* alpha       = (const float*)d_in[8];
  const float* w1          = (const float*)d_in[9];
  const float* w2          = (const float*)d_in[10];
  const int*   is_text     = (const int*)d_in[11];
  float* out = (float*)d_out;

  char* ws = (char*)d_ws;
  u16* w1b = (u16*)(ws + 0);
  u16* w2b = (u16*)(ws + 67108864);
  u16* Xg  = (u16*)(ws + 134217728);
  u16* Hb  = (u16*)(ws + 151519232);
  float4* sel_w   = (float4*)(ws + 220725248);
  float* pair_w   = (float*)(ws + 220725248 + 65536);
  int* pair_idx   = (int*)(ws + 220725248 + 98816);
  float* prob_part= (float*)(ws + 220725248 + 131584);
  int* count_part = (int*)(ws + 220725248 + 164352);
  int* counters   = (int*)(ws + 220725248 + 197120);
  float* pair_out = (float*)(ws + 0);  // 2 parts, aliases dead w1b

  int* counts  = counters;
  int* offs    = counters + 8;
  int* cursors = counters + 16;

  convtrans<D_, H_><<<dim3(H_/64, D_/64, E_), 256, 0, stream>>>(w1, w1b);
  convtrans<H_, D_><<<dim3(D_/64, H_/64, E_), 256, 0, stream>>>(w2, w2b);
  gating<<<dim3(T_/4), 256, 0, stream>>>(inputs, task_param, gate_img_w, gate_img_b,
      gate_txt_w, gate_txt_b, task_gate_w, task_gate_b, alpha, is_text,
      sel_w, prob_part, count_part);
  finalize<<<dim3(1), 256, 0, stream>>>(prob_part, count_part, counts, offs, cursors,
      out + (size_t)T_ * D_);
  scatter_gather<<<dim3(T_/4), 256, 0, stream>>>(inputs, sel_w, cursors, pair_w, pair_idx, Xg);
  // GEMM1: Tok=Xg, W=w1b; K=1024 (no split), 16 panels, 2 token-slots. 256 blocks.
  gemm256<0, D_, D_, H_, 16, 1, 2><<<dim3(256), 512, 0, stream>>>(
      Xg, w1b, counts, offs, pair_w, Hb, (float*)nullptr);
  // GEMM2: Tok=Hb, W=w2b; K=4096 split 2x2048, 4 panels, 4 token-slots. 256 blocks.
  gemm256<1, H_, H_/2, D_, 4, 2, 4><<<dim3(256), 512, 0, stream>>>(
      Hb, w2b, counts, offs, pair_w, (u16*)nullptr, pair_out);
  combine<<<dim3(T_), 256, 0, stream>>>(pair_out, pair_idx, out);
}